// Round 7
// baseline (65.376 us; speedup 1.0000x reference)
//
#include <hip/hip_runtime.h>

#define NB   8192
#define NA   32
#define DIN  8
#define HID  64
#define DOUT 8

typedef float     v4f __attribute__((ext_vector_type(4)));
typedef _Float16  v4h __attribute__((ext_vector_type(4)));

__device__ __forceinline__ float silu_f(float x) {
    return __fdividef(x, 1.0f + __expf(-x));
}

__device__ __forceinline__ v4h cvt4(v4f a) {   // RNE converts
    v4h r;
    r[0] = (_Float16)a[0]; r[1] = (_Float16)a[1];
    r[2] = (_Float16)a[2]; r[3] = (_Float16)a[3];
    return r;
}

__device__ __forceinline__ v4h silu_cvt4(v4f a) {
    v4f s;
    s[0] = silu_f(a[0]); s[1] = silu_f(a[1]);
    s[2] = silu_f(a[2]); s[3] = silu_f(a[3]);
    return cvt4(s);
}

#define MFMA16(A, B, C) __builtin_amdgcn_mfma_f32_16x16x16f16((A), (B), (C), 0, 0, 0)

// One wave = one batch item, fully in MFMA fragments.
// C-frag (col=l&15, row=4*(l>>4)+r) chains directly as next stage's A/B frag.
// hlds rows are XOR-swizzled: phys = row ^ ((row>>4)&3) -> conflict-free writes.
__global__ __launch_bounds__(256, 5) void attn_mfma_kernel(
    const float* __restrict__ x,      // (NB, NA, DIN)
    const float* __restrict__ lap,    // (NB, NA)
    const float* __restrict__ W_in,   // (HID, DIN)
    const float* __restrict__ b_in,   // (HID)
    const float* __restrict__ Aq,     // (HID, HID)
    const float* __restrict__ Ak,     // (HID, HID)
    const float* __restrict__ Av,     // (HID, HID)
    const float* __restrict__ W_out,  // (DOUT, HID)
    const float* __restrict__ b_out,  // (DOUT)
    float* __restrict__ out)          // (NB, DOUT)
{
    // Frag-ordered f16 weights: [mat][frag = it*4+ks][lane][4]   (24 KB)
    __shared__ _Float16 wlds[3][16][64][4];
    // Per-wave h transpose staging, one nt at a time: [wave][jt][64][4] (8 KB)
    __shared__ _Float16 hlds[4][4][64][4];

    const int t  = threadIdx.x;
    const int l  = t & 63;
    const int w  = t >> 6;
    const int lm = l & 15;
    const int lg = l >> 4;

    // ---- stage Aq/Ak/Av into LDS as f16 frags (once per block) ----
    {
        const float* mats[3] = {Aq, Ak, Av};
        #pragma unroll
        for (int m = 0; m < 3; ++m) {
            #pragma unroll
            for (int f = 0; f < 4; ++f) {
                const int fid = w * 4 + f;
                const int it = fid >> 2, ks = fid & 3;
                v4f v = *(const v4f*)(mats[m] + (lm + 16 * it) * 64 + 16 * ks + 4 * lg);
                *(v4h*)&wlds[m][fid][l][0] = cvt4(v);
            }
        }
    }

    // ---- persistent register frags ----
    v4h zh = {};
    v4f zf = {};
    v4h winf[4];
    #pragma unroll
    for (int jt = 0; jt < 4; ++jt)
        winf[jt] = (lg < 2) ? cvt4(*(const v4f*)(W_in + (lm + 16 * jt) * 8 + 4 * lg)) : zh;
    v4h woutf[4];
    #pragma unroll
    for (int ks = 0; ks < 4; ++ks)
        woutf[ks] = (lm < 8) ? cvt4(*(const v4f*)(W_out + lm * 64 + 16 * ks + 4 * lg)) : zh;
    float binf[4];
    #pragma unroll
    for (int jt = 0; jt < 4; ++jt) binf[jt] = b_in[lm + 16 * jt];
    const float boutf = (lm < 8) ? b_out[lm] : 0.0f;

    __syncthreads();   // the only block barrier

    const int b = blockIdx.x * 4 + w;   // one item per wave, 2048*4 == NB

    v4f lapv[2];
    lapv[0] = *(const v4f*)(lap + b * 32 + 4 * lg);
    lapv[1] = *(const v4f*)(lap + b * 32 + 16 + 4 * lg);

    v4h xf[2];
    #pragma unroll
    for (int nt = 0; nt < 2; ++nt)
        xf[nt] = (lg < 2) ? cvt4(*(const v4f*)(x + b * 256 + (lm + 16 * nt) * 8 + 4 * lg)) : zh;

    // ---- h = silu(x @ W_in^T + b_in) * lap ; C->A transpose via swizzled LDS ----
    const int pr = l ^ lg;              // reader's swizzled row: l ^ ((l>>4)&3)
    v4h hf[2][4];
    #pragma unroll
    for (int nt = 0; nt < 2; ++nt) {
        #pragma unroll
        for (int jt = 0; jt < 4; ++jt) {
            v4f hc = MFMA16(xf[nt], winf[jt], zf);   // col j=lm+16jt, row n=4lg+r+16nt
            #pragma unroll
            for (int r = 0; r < 4; ++r) {
                float hv = silu_f(hc[r] + binf[jt]) * lapv[nt][r];
                const int lr   = (4 * lg + r) | ((lm >> 2) << 4);
                const int phys = lr ^ (lm >> 2);     // XOR swizzle (row ^ row>>4)
                hlds[w][jt][phys][lm & 3] = (_Float16)hv;
            }
        }
        __builtin_amdgcn_s_waitcnt(0);   // ds writes visible to same wave
        #pragma unroll
        for (int ks = 0; ks < 4; ++ks)
            hf[nt][ks] = *(v4h*)&hlds[w][ks][pr][0];
        __builtin_amdgcn_s_waitcnt(0);   // reads landed before next nt overwrites
    }

    // ---- QT[n][i] = silu(h @ Aq^T) ----
    v4h qf[2][4];
    {
        v4f acc[2][4] = {};
        #pragma unroll
        for (int it = 0; it < 4; ++it)
            #pragma unroll
            for (int ks = 0; ks < 4; ++ks) {
                v4h bw = *(v4h*)&wlds[0][it * 4 + ks][l][0];
                #pragma unroll
                for (int nt = 0; nt < 2; ++nt)
                    acc[nt][it] = MFMA16(hf[nt][ks], bw, acc[nt][it]);
            }
        #pragma unroll
        for (int nt = 0; nt < 2; ++nt)
            #pragma unroll
            for (int it = 0; it < 4; ++it) qf[nt][it] = silu_cvt4(acc[nt][it]);
    }
    // ---- KT[n][i] = silu(h @ Ak^T) ----
    v4h kf[2][4];
    {
        v4f acc[2][4] = {};
        #pragma unroll
        for (int it = 0; it < 4; ++it)
            #pragma unroll
            for (int ks = 0; ks < 4; ++ks) {
                v4h bw = *(v4h*)&wlds[1][it * 4 + ks][l][0];
                #pragma unroll
                for (int nt = 0; nt < 2; ++nt)
                    acc[nt][it] = MFMA16(hf[nt][ks], bw, acc[nt][it]);
            }
        #pragma unroll
        for (int nt = 0; nt < 2; ++nt)
            #pragma unroll
            for (int it = 0; it < 4; ++it) kf[nt][it] = silu_cvt4(acc[nt][it]);
    }
    // ---- V[i][n] = silu(Av @ h^T) ----
    v4h vf[4][2];
    {
        v4f acc[4][2] = {};
        #pragma unroll
        for (int it = 0; it < 4; ++it)
            #pragma unroll
            for (int ks = 0; ks < 4; ++ks) {
                v4h aw = *(v4h*)&wlds[2][it * 4 + ks][l][0];
                #pragma unroll
                for (int nt = 0; nt < 2; ++nt)
                    acc[it][nt] = MFMA16(aw, hf[nt][ks], acc[it][nt]);
            }
        #pragma unroll
        for (int it = 0; it < 4; ++it)
            #pragma unroll
            for (int nt = 0; nt < 2; ++nt) vf[it][nt] = silu_cvt4(acc[it][nt]);
    }

    // ---- S^T[j][i] = K^T(j,n) @ Q(n,i) ----
    v4f st[4][4] = {};
    #pragma unroll
    for (int jt = 0; jt < 4; ++jt)
        #pragma unroll
        for (int it = 0; it < 4; ++it)
            #pragma unroll
            for (int ns = 0; ns < 2; ++ns)
                st[jt][it] = MFMA16(kf[ns][jt], qf[ns][it], st[jt][it]);

    // ---- softmax over j (regs + 2 shfls), P -> PV A-frags ----
    v4h pf[4][4];
    #pragma unroll
    for (int it = 0; it < 4; ++it) {
        float mx = st[0][it][0];
        #pragma unroll
        for (int jt = 0; jt < 4; ++jt)
            #pragma unroll
            for (int r = 0; r < 4; ++r) mx = fmaxf(mx, st[jt][it][r]);
        mx = fmaxf(mx, __shfl_xor(mx, 16, 64));
        mx = fmaxf(mx, __shfl_xor(mx, 32, 64));
        float sum = 0.0f;
        #pragma unroll
        for (int jt = 0; jt < 4; ++jt)
            #pragma unroll
            for (int r = 0; r < 4; ++r) {
                float e = __expf(st[jt][it][r] - mx);
                st[jt][it][r] = e;
                sum += e;
            }
        sum += __shfl_xor(sum, 16, 64);
        sum += __shfl_xor(sum, 32, 64);
        const float inv = __fdividef(1.0f, sum);
        #pragma unroll
        for (int jt = 0; jt < 4; ++jt) {
            v4f p = st[jt][it] * inv;
            pf[it][jt] = cvt4(p);
        }
    }

    // ---- attnM[i][n] = P(i,j) @ V(j,n) ----
    v4f pv[4][2] = {};
    #pragma unroll
    for (int it = 0; it < 4; ++it)
        #pragma unroll
        for (int js = 0; js < 4; ++js)
            #pragma unroll
            for (int nt = 0; nt < 2; ++nt)
                pv[it][nt] = MFMA16(pf[it][js], vf[js][nt], pv[it][nt]);

    // ---- y = silu(attn @ W_out^T + b_out) * lap ; mean over n ----
    v4f ya[2] = {};
    #pragma unroll
    for (int nt = 0; nt < 2; ++nt)
        #pragma unroll
        for (int is = 0; is < 4; ++is)
            ya[nt] = MFMA16(silu_cvt4(pv[is][nt]), woutf[is], ya[nt]);

    float acc = 0.0f;
    #pragma unroll
    for (int nt = 0; nt < 2; ++nt)
        #pragma unroll
        for (int r = 0; r < 4; ++r)
            acc += silu_f(ya[nt][r] + boutf) * lapv[nt][r];
    acc += __shfl_xor(acc, 16, 64);
    acc += __shfl_xor(acc, 32, 64);
    if (l < 8) out[b * DOUT + l] = acc * (1.0f / NA);
}

extern "C" void kernel_launch(void* const* d_in, const int* in_sizes, int n_in,
                              void* d_out, int out_size, void* d_ws, size_t ws_size,
                              hipStream_t stream) {
    const float* x     = (const float*)d_in[0];
    const float* lap   = (const float*)d_in[1];
    const float* W_in  = (const float*)d_in[2];
    const float* b_in  = (const float*)d_in[3];
    const float* Aq    = (const float*)d_in[4];
    const float* Ak    = (const float*)d_in[5];
    const float* Av    = (const float*)d_in[6];
    const float* W_out = (const float*)d_in[7];
    const float* b_out = (const float*)d_in[8];
    attn_mfma_kernel<<<2048, 256, 0, stream>>>(x, lap, W_in, b_in, Aq, Ak, Av,
                                               W_out, b_out, (float*)d_out);
}

// Round 8
// 62.208 us; speedup vs baseline: 1.0509x; 1.0509x over previous
//
#include <hip/hip_runtime.h>

#define NB   8192
#define NA   32
#define DIN  8
#define HID  64
#define DOUT 8

typedef float     v4f __attribute__((ext_vector_type(4)));
typedef _Float16  v4h __attribute__((ext_vector_type(4)));

__device__ __forceinline__ float silu_f(float x) {
    return __fdividef(x, 1.0f + __expf(-x));
}

__device__ __forceinline__ v4h cvt4(v4f a) {   // RNE converts
    v4h r;
    r[0] = (_Float16)a[0]; r[1] = (_Float16)a[1];
    r[2] = (_Float16)a[2]; r[3] = (_Float16)a[3];
    return r;
}

__device__ __forceinline__ v4h silu_cvt4(v4f a) {
    v4f s;
    s[0] = silu_f(a[0]); s[1] = silu_f(a[1]);
    s[2] = silu_f(a[2]); s[3] = silu_f(a[3]);
    return cvt4(s);
}

#define MFMA16(A, B, C) __builtin_amdgcn_mfma_f32_16x16x16f16((A), (B), (C), 0, 0, 0)

// One wave = one batch item, fully in MFMA fragments.
// C-frag (col=l&15, row=4*(l>>4)+r) chains directly as next stage's A/B frag.
// Attention tail is streamed per i-tile (S-col -> softmax -> PV -> Wout-acc)
// to keep the live register set ~100 VGPRs (r7's (256,5) bound caused spills:
// VGPR=48, WRITE_SIZE=37MB scratch traffic).
__global__ __launch_bounds__(256, 4) void attn_mfma_kernel(
    const float* __restrict__ x,      // (NB, NA, DIN)
    const float* __restrict__ lap,    // (NB, NA)
    const float* __restrict__ W_in,   // (HID, DIN)
    const float* __restrict__ b_in,   // (HID)
    const float* __restrict__ Aq,     // (HID, HID)
    const float* __restrict__ Ak,     // (HID, HID)
    const float* __restrict__ Av,     // (HID, HID)
    const float* __restrict__ W_out,  // (DOUT, HID)
    const float* __restrict__ b_out,  // (DOUT)
    float* __restrict__ out)          // (NB, DOUT)
{
    // Frag-ordered f16 weights: [mat][frag = it*4+ks][lane][4]   (24 KB)
    __shared__ _Float16 wlds[3][16][64][4];
    // Per-wave h transpose staging: [wave][jt][64][4]            (8 KB)
    __shared__ _Float16 hlds[4][4][64][4];

    const int t  = threadIdx.x;
    const int l  = t & 63;
    const int w  = t >> 6;
    const int lm = l & 15;
    const int lg = l >> 4;

    // ---- stage Aq/Ak/Av into LDS as f16 frags (once per block) ----
    {
        const float* mats[3] = {Aq, Ak, Av};
        #pragma unroll
        for (int m = 0; m < 3; ++m) {
            #pragma unroll
            for (int f = 0; f < 4; ++f) {
                const int fid = w * 4 + f;
                const int it = fid >> 2, ks = fid & 3;
                v4f v = *(const v4f*)(mats[m] + (lm + 16 * it) * 64 + 16 * ks + 4 * lg);
                *(v4h*)&wlds[m][fid][l][0] = cvt4(v);
            }
        }
    }

    // ---- persistent register frags ----
    v4h zh = {};
    v4f zf = {};
    v4h winf[4];
    #pragma unroll
    for (int jt = 0; jt < 4; ++jt)
        winf[jt] = (lg < 2) ? cvt4(*(const v4f*)(W_in + (lm + 16 * jt) * 8 + 4 * lg)) : zh;
    v4h woutf[4];
    #pragma unroll
    for (int ks = 0; ks < 4; ++ks)
        woutf[ks] = (lm < 8) ? cvt4(*(const v4f*)(W_out + lm * 64 + 16 * ks + 4 * lg)) : zh;
    float binf[4];
    #pragma unroll
    for (int jt = 0; jt < 4; ++jt) binf[jt] = b_in[lm + 16 * jt];
    const float boutf = (lm < 8) ? b_out[lm] : 0.0f;

    __syncthreads();   // the only block barrier

    const int b = blockIdx.x * 4 + w;   // one item per wave, 2048*4 == NB

    v4f lapv[2];
    lapv[0] = *(const v4f*)(lap + b * 32 + 4 * lg);
    lapv[1] = *(const v4f*)(lap + b * 32 + 16 + 4 * lg);

    v4h xf[2];
    #pragma unroll
    for (int nt = 0; nt < 2; ++nt)
        xf[nt] = (lg < 2) ? cvt4(*(const v4f*)(x + b * 256 + (lm + 16 * nt) * 8 + 4 * lg)) : zh;

    // ---- h = silu(x @ W_in^T + b_in) * lap ; C->A transpose via swizzled LDS ----
    const int pr = l ^ lg;              // reader's swizzled row: l ^ ((l>>4)&3)
    v4h hf[2][4];
    #pragma unroll
    for (int nt = 0; nt < 2; ++nt) {
        #pragma unroll
        for (int jt = 0; jt < 4; ++jt) {
            v4f hc = MFMA16(xf[nt], winf[jt], zf);   // col j=lm+16jt, row n=4lg+r+16nt
            #pragma unroll
            for (int r = 0; r < 4; ++r) {
                float hv = silu_f(hc[r] + binf[jt]) * lapv[nt][r];
                const int lr   = (4 * lg + r) | ((lm >> 2) << 4);
                const int phys = lr ^ (lm >> 2);     // XOR swizzle (row ^ row>>4)
                hlds[w][jt][phys][lm & 3] = (_Float16)hv;
            }
        }
        __builtin_amdgcn_s_waitcnt(0);   // ds writes visible to same wave
        #pragma unroll
        for (int ks = 0; ks < 4; ++ks)
            hf[nt][ks] = *(v4h*)&hlds[w][ks][pr][0];
        __builtin_amdgcn_s_waitcnt(0);   // reads landed before next nt overwrites
    }

    // ---- QT[n][i] = silu(h @ Aq^T)  (per-nt acc: 16 live acc regs) ----
    v4h qf[2][4];
    #pragma unroll
    for (int nt = 0; nt < 2; ++nt) {
        v4f acc[4] = {};
        #pragma unroll
        for (int it = 0; it < 4; ++it)
            #pragma unroll
            for (int ks = 0; ks < 4; ++ks)
                acc[it] = MFMA16(hf[nt][ks], *(v4h*)&wlds[0][it * 4 + ks][l][0], acc[it]);
        #pragma unroll
        for (int it = 0; it < 4; ++it) qf[nt][it] = silu_cvt4(acc[it]);
    }
    // ---- KT[n][i] = silu(h @ Ak^T) ----
    v4h kf[2][4];
    #pragma unroll
    for (int nt = 0; nt < 2; ++nt) {
        v4f acc[4] = {};
        #pragma unroll
        for (int it = 0; it < 4; ++it)
            #pragma unroll
            for (int ks = 0; ks < 4; ++ks)
                acc[it] = MFMA16(hf[nt][ks], *(v4h*)&wlds[1][it * 4 + ks][l][0], acc[it]);
        #pragma unroll
        for (int it = 0; it < 4; ++it) kf[nt][it] = silu_cvt4(acc[it]);
    }
    // ---- V[i][n] = silu(Av @ h^T) ----
    v4h vf[4][2];
    #pragma unroll
    for (int nt = 0; nt < 2; ++nt) {
        v4f acc[4] = {};
        #pragma unroll
        for (int it = 0; it < 4; ++it)
            #pragma unroll
            for (int ks = 0; ks < 4; ++ks)
                acc[it] = MFMA16(*(v4h*)&wlds[2][it * 4 + ks][l][0], hf[nt][ks], acc[it]);
        #pragma unroll
        for (int it = 0; it < 4; ++it) vf[it][nt] = silu_cvt4(acc[it]);
    }

    // ---- streamed tail: per i-tile, S-col -> softmax -> PV -> Wout-acc ----
    v4f ya[2] = {};
    #pragma unroll
    for (int it = 0; it < 4; ++it) {
        // S^T column block: row j=4lg+r+16jt, col i=lm+16it
        v4f s[4] = {};
        #pragma unroll
        for (int jt = 0; jt < 4; ++jt)
            #pragma unroll
            for (int ns = 0; ns < 2; ++ns)
                s[jt] = MFMA16(kf[ns][jt], qf[ns][it], s[jt]);

        // softmax over j (16 reg values + lane-groups 16/32)
        float mx = s[0][0];
        #pragma unroll
        for (int jt = 0; jt < 4; ++jt)
            #pragma unroll
            for (int r = 0; r < 4; ++r) mx = fmaxf(mx, s[jt][r]);
        mx = fmaxf(mx, __shfl_xor(mx, 16, 64));
        mx = fmaxf(mx, __shfl_xor(mx, 32, 64));
        float sum = 0.0f;
        #pragma unroll
        for (int jt = 0; jt < 4; ++jt)
            #pragma unroll
            for (int r = 0; r < 4; ++r) {
                float e = __expf(s[jt][r] - mx);
                s[jt][r] = e;
                sum += e;
            }
        sum += __shfl_xor(sum, 16, 64);
        sum += __shfl_xor(sum, 32, 64);
        const float inv = __fdividef(1.0f, sum);
        v4h pf[4];
        #pragma unroll
        for (int jt = 0; jt < 4; ++jt) pf[jt] = cvt4(s[jt] * inv);

        // PV for this i-tile: attnM[i][n] = P(i,j) @ V(j,n)
        v4f pv[2] = {};
        #pragma unroll
        for (int js = 0; js < 4; ++js)
            #pragma unroll
            for (int nt = 0; nt < 2; ++nt)
                pv[nt] = MFMA16(pf[js], vf[js][nt], pv[nt]);

        // y-acc: ya[nt] += silu(attn) @ W_out^T (k-slice = this i-tile)
        #pragma unroll
        for (int nt = 0; nt < 2; ++nt)
            ya[nt] = MFMA16(silu_cvt4(pv[nt]), woutf[it], ya[nt]);
    }

    // ---- y = silu(ya + b_out) * lap ; mean over n ----
    float acc = 0.0f;
    #pragma unroll
    for (int nt = 0; nt < 2; ++nt)
        #pragma unroll
        for (int r = 0; r < 4; ++r)
            acc += silu_f(ya[nt][r] + boutf) * lapv[nt][r];
    acc += __shfl_xor(acc, 16, 64);
    acc += __shfl_xor(acc, 32, 64);
    if (l < 8) out[b * DOUT + l] = acc * (1.0f / NA);
}

extern "C" void kernel_launch(void* const* d_in, const int* in_sizes, int n_in,
                              void* d_out, int out_size, void* d_ws, size_t ws_size,
                              hipStream_t stream) {
    const float* x     = (const float*)d_in[0];
    const float* lap   = (const float*)d_in[1];
    const float* W_in  = (const float*)d_in[2];
    const float* b_in  = (const float*)d_in[3];
    const float* Aq    = (const float*)d_in[4];
    const float* Ak    = (const float*)d_in[5];
    const float* Av    = (const float*)d_in[6];
    const float* W_out = (const float*)d_in[7];
    const float* b_out = (const float*)d_in[8];
    attn_mfma_kernel<<<2048, 256, 0, stream>>>(x, lap, W_in, b_in, Aq, Ak, Av,
                                               W_out, b_out, (float*)d_out);
}

// Round 10
// 60.207 us; speedup vs baseline: 1.0859x; 1.0332x over previous
//
#include <hip/hip_runtime.h>

#define NB   8192
#define NA   32
#define DIN  8
#define HID  64
#define DOUT 8

typedef float     v4f __attribute__((ext_vector_type(4)));
typedef _Float16  v4h __attribute__((ext_vector_type(4)));

__device__ __forceinline__ float silu_f(float x) {
    return __fdividef(x, 1.0f + __expf(-x));
}

__device__ __forceinline__ v4h cvt4(v4f a) {   // RNE converts
    v4h r;
    r[0] = (_Float16)a[0]; r[1] = (_Float16)a[1];
    r[2] = (_Float16)a[2]; r[3] = (_Float16)a[3];
    return r;
}

__device__ __forceinline__ v4h silu_cvt4(v4f a) {
    v4f s;
    s[0] = silu_f(a[0]); s[1] = silu_f(a[1]);
    s[2] = silu_f(a[2]); s[3] = silu_f(a[3]);
    return cvt4(s);
}

#define MFMA16(A, B, C) __builtin_amdgcn_mfma_f32_16x16x16f16((A), (B), (C), 0, 0, 0)

// One wave = one batch item, fully in MFMA fragments.
// 512-thread blocks: 8 waves share the 24KB weight LDS -> 40KB/block
// -> 4 blocks/CU -> 32 waves/CU theoretical occupancy (was 20).
// Weight frags are ds_read ONCE per item (applied to both nt halves).
// Attention tail streamed per i-tile to bound live registers (~110).
__global__ __launch_bounds__(512, 4) void attn_mfma_kernel(
    const float* __restrict__ x,      // (NB, NA, DIN)
    const float* __restrict__ lap,    // (NB, NA)
    const float* __restrict__ W_in,   // (HID, DIN)
    const float* __restrict__ b_in,   // (HID)
    const float* __restrict__ Aq,     // (HID, HID)
    const float* __restrict__ Ak,     // (HID, HID)
    const float* __restrict__ Av,     // (HID, HID)
    const float* __restrict__ W_out,  // (DOUT, HID)
    const float* __restrict__ b_out,  // (DOUT)
    float* __restrict__ out)          // (NB, DOUT)
{
    // Frag-ordered f16 weights: [mat][frag = it*4+ks][lane][4]   (24 KB)
    __shared__ _Float16 wlds[3][16][64][4];
    // Per-wave h transpose staging: [wave][jt][64][4]            (16 KB)
    __shared__ _Float16 hlds[8][4][64][4];

    const int t  = threadIdx.x;
    const int l  = t & 63;
    const int w  = t >> 6;          // 0..7
    const int lm = l & 15;
    const int lg = l >> 4;

    // ---- stage Aq/Ak/Av into LDS as f16 frags (once per block; 2 frags/wave) ----
    {
        const float* mats[3] = {Aq, Ak, Av};
        #pragma unroll
        for (int m = 0; m < 3; ++m) {
            #pragma unroll
            for (int f = 0; f < 2; ++f) {
                const int fid = w * 2 + f;
                const int it = fid >> 2, ks = fid & 3;
                v4f v = *(const v4f*)(mats[m] + (lm + 16 * it) * 64 + 16 * ks + 4 * lg);
                *(v4h*)&wlds[m][fid][l][0] = cvt4(v);
            }
        }
    }

    // ---- persistent register frags ----
    v4h zh = {};
    v4f zf = {};
    v4h winf[4];
    #pragma unroll
    for (int jt = 0; jt < 4; ++jt)
        winf[jt] = (lg < 2) ? cvt4(*(const v4f*)(W_in + (lm + 16 * jt) * 8 + 4 * lg)) : zh;
    v4h woutf[4];
    #pragma unroll
    for (int ks = 0; ks < 4; ++ks)
        woutf[ks] = (lm < 8) ? cvt4(*(const v4f*)(W_out + lm * 64 + 16 * ks + 4 * lg)) : zh;
    float binf[4];
    #pragma unroll
    for (int jt = 0; jt < 4; ++jt) binf[jt] = b_in[lm + 16 * jt];
    const float boutf = (lm < 8) ? b_out[lm] : 0.0f;

    __syncthreads();   // the only block barrier

    const int b = blockIdx.x * 8 + w;   // one item per wave, 1024*8 == NB

    v4f lapv[2];
    lapv[0] = *(const v4f*)(lap + b * 32 + 4 * lg);
    lapv[1] = *(const v4f*)(lap + b * 32 + 16 + 4 * lg);

    v4h xf[2];
    #pragma unroll
    for (int nt = 0; nt < 2; ++nt)
        xf[nt] = (lg < 2) ? cvt4(*(const v4f*)(x + b * 256 + (lm + 16 * nt) * 8 + 4 * lg)) : zh;

    // ---- h = silu(x @ W_in^T + b_in) * lap ; C->A transpose via swizzled LDS ----
    const int pr = l ^ lg;              // reader's swizzled row: l ^ ((l>>4)&3)
    v4h hf[2][4];
    #pragma unroll
    for (int nt = 0; nt < 2; ++nt) {
        #pragma unroll
        for (int jt = 0; jt < 4; ++jt) {
            v4f hc = MFMA16(xf[nt], winf[jt], zf);   // col j=lm+16jt, row n=4lg+r+16nt
            #pragma unroll
            for (int r = 0; r < 4; ++r) {
                float hv = silu_f(hc[r] + binf[jt]) * lapv[nt][r];
                const int lr   = (4 * lg + r) | ((lm >> 2) << 4);
                const int phys = lr ^ (lm >> 2);     // XOR swizzle (row ^ row>>4)
                hlds[w][jt][phys][lm & 3] = (_Float16)hv;
            }
        }
        __builtin_amdgcn_s_waitcnt(0);   // ds writes visible to same wave
        #pragma unroll
        for (int ks = 0; ks < 4; ++ks)
            hf[nt][ks] = *(v4h*)&hlds[w][ks][pr][0];
        __builtin_amdgcn_s_waitcnt(0);   // reads landed before next nt overwrites
    }

    // ---- QT[n][i] = silu(h @ Aq^T)  (each weight frag read once) ----
    v4h qf[2][4];
    {
        v4f acc[2][4] = {};
        #pragma unroll
        for (int it = 0; it < 4; ++it)
            #pragma unroll
            for (int ks = 0; ks < 4; ++ks) {
                v4h bw = *(v4h*)&wlds[0][it * 4 + ks][l][0];
                #pragma unroll
                for (int nt = 0; nt < 2; ++nt)
                    acc[nt][it] = MFMA16(hf[nt][ks], bw, acc[nt][it]);
            }
        #pragma unroll
        for (int nt = 0; nt < 2; ++nt)
            #pragma unroll
            for (int it = 0; it < 4; ++it) qf[nt][it] = silu_cvt4(acc[nt][it]);
    }
    // ---- KT[n][i] = silu(h @ Ak^T) ----
    v4h kf[2][4];
    {
        v4f acc[2][4] = {};
        #pragma unroll
        for (int it = 0; it < 4; ++it)
            #pragma unroll
            for (int ks = 0; ks < 4; ++ks) {
                v4h bw = *(v4h*)&wlds[1][it * 4 + ks][l][0];
                #pragma unroll
                for (int nt = 0; nt < 2; ++nt)
                    acc[nt][it] = MFMA16(hf[nt][ks], bw, acc[nt][it]);
            }
        #pragma unroll
        for (int nt = 0; nt < 2; ++nt)
            #pragma unroll
            for (int it = 0; it < 4; ++it) kf[nt][it] = silu_cvt4(acc[nt][it]);
    }
    // ---- V[i][n] = silu(Av @ h^T) ----
    v4h vf[4][2];
    {
        v4f acc[4][2] = {};
        #pragma unroll
        for (int it = 0; it < 4; ++it)
            #pragma unroll
            for (int ks = 0; ks < 4; ++ks) {
                v4h aw = *(v4h*)&wlds[2][it * 4 + ks][l][0];
                #pragma unroll
                for (int nt = 0; nt < 2; ++nt)
                    acc[it][nt] = MFMA16(aw, hf[nt][ks], acc[it][nt]);
            }
        #pragma unroll
        for (int it = 0; it < 4; ++it)
            #pragma unroll
            for (int nt = 0; nt < 2; ++nt) vf[it][nt] = silu_cvt4(acc[it][nt]);
    }

    // ---- streamed tail: per i-tile, S-col -> softmax -> PV -> Wout-acc ----
    v4f ya[2] = {};
    #pragma unroll
    for (int it = 0; it < 4; ++it) {
        // S^T column block: row j=4lg+r+16jt, col i=lm+16it
        v4f s[4] = {};
        #pragma unroll
        for (int jt = 0; jt < 4; ++jt)
            #pragma unroll
            for (int ns = 0; ns < 2; ++ns)
                s[jt] = MFMA16(kf[ns][jt], qf[ns][it], s[jt]);

        // softmax over j (16 reg values + lane-groups 16/32)
        float mx = s[0][0];
        #pragma unroll
        for (int jt = 0; jt < 4; ++jt)
            #pragma unroll
            for (int r = 0; r < 4; ++r) mx = fmaxf(mx, s[jt][r]);
        mx = fmaxf(mx, __shfl_xor(mx, 16, 64));
        mx = fmaxf(mx, __shfl_xor(mx, 32, 64));
        float sum = 0.0f;
        #pragma unroll
        for (int jt = 0; jt < 4; ++jt)
            #pragma unroll
            for (int r = 0; r < 4; ++r) {
                float e = __expf(s[jt][r] - mx);
                s[jt][r] = e;
                sum += e;
            }
        sum += __shfl_xor(sum, 16, 64);
        sum += __shfl_xor(sum, 32, 64);
        const float inv = __fdividef(1.0f, sum);
        v4h pf[4];
        #pragma unroll
        for (int jt = 0; jt < 4; ++jt) pf[jt] = cvt4(s[jt] * inv);

        // PV for this i-tile: attnM[i][n] = P(i,j) @ V(j,n)
        v4f pv[2] = {};
        #pragma unroll
        for (int js = 0; js < 4; ++js)
            #pragma unroll
            for (int nt = 0; nt < 2; ++nt)
                pv[nt] = MFMA16(pf[js], vf[js][nt], pv[nt]);

        // y-acc: ya[nt] += silu(attn) @ W_out^T (k-slice = this i-tile)
        #pragma unroll
        for (int nt = 0; nt < 2; ++nt)
            ya[nt] = MFMA16(silu_cvt4(pv[nt]), woutf[it], ya[nt]);
    }

    // ---- y = silu(ya + b_out) * lap ; mean over n ----
    float acc = 0.0f;
    #pragma unroll
    for (int nt = 0; nt < 2; ++nt)
        #pragma unroll
        for (int r = 0; r < 4; ++r)
            acc += silu_f(ya[nt][r] + boutf) * lapv[nt][r];
    acc += __shfl_xor(acc, 16, 64);
    acc += __shfl_xor(acc, 32, 64);
    if (l < 8) out[b * DOUT + l] = acc * (1.0f / NA);
}

extern "C" void kernel_launch(void* const* d_in, const int* in_sizes, int n_in,
                              void* d_out, int out_size, void* d_ws, size_t ws_size,
                              hipStream_t stream) {
    const float* x     = (const float*)d_in[0];
    const float* lap   = (const float*)d_in[1];
    const float* W_in  = (const float*)d_in[2];
    const float* b_in  = (const float*)d_in[3];
    const float* Aq    = (const float*)d_in[4];
    const float* Ak    = (const float*)d_in[5];
    const float* Av    = (const float*)d_in[6];
    const float* W_out = (const float*)d_in[7];
    const float* b_out = (const float*)d_in[8];
    attn_mfma_kernel<<<1024, 512, 0, stream>>>(x, lap, W_in, b_in, Aq, Ak, Av,
                                               W_out, b_out, (float*)d_out);
}

// Round 11
// 58.694 us; speedup vs baseline: 1.1139x; 1.0258x over previous
//
#include <hip/hip_runtime.h>

#define NB   8192
#define NA   32
#define DIN  8
#define HID  64
#define DOUT 8

typedef float     v4f __attribute__((ext_vector_type(4)));
typedef _Float16  v4h __attribute__((ext_vector_type(4)));
typedef _Float16  v8h __attribute__((ext_vector_type(8)));

__device__ __forceinline__ float silu_f(float x) {
    return __fdividef(x, 1.0f + __expf(-x));
}

__device__ __forceinline__ v4h cvt4(v4f a) {   // RNE converts
    v4h r;
    r[0] = (_Float16)a[0]; r[1] = (_Float16)a[1];
    r[2] = (_Float16)a[2]; r[3] = (_Float16)a[3];
    return r;
}

__device__ __forceinline__ v8h cvt8(v4f a, v4f b) {
    v8h r;
    r[0] = (_Float16)a[0]; r[1] = (_Float16)a[1];
    r[2] = (_Float16)a[2]; r[3] = (_Float16)a[3];
    r[4] = (_Float16)b[0]; r[5] = (_Float16)b[1];
    r[6] = (_Float16)b[2]; r[7] = (_Float16)b[3];
    return r;
}

__device__ __forceinline__ v4h silu_cvt4(v4f a) {
    v4f s;
    s[0] = silu_f(a[0]); s[1] = silu_f(a[1]);
    s[2] = silu_f(a[2]); s[3] = silu_f(a[3]);
    return cvt4(s);
}

__device__ __forceinline__ v8h cat(v4h a, v4h b) {
    return __builtin_shufflevector(a, b, 0, 1, 2, 3, 4, 5, 6, 7);
}

#define MFMA16(A, B, C) __builtin_amdgcn_mfma_f32_16x16x16f16((A), (B), (C), 0, 0, 0)
#define MFMA32(A, B, C) __builtin_amdgcn_mfma_f32_16x16x32_f16((A), (B), (C), 0, 0, 0)

// One wave = one batch item, fully in MFMA fragments.
// K=32 MFMAs: operand v8h = concat of the two K=16 fragment halves
// (k = 4*lg + (r&3) + 16*(r>>2)), so existing frag pairs chain directly.
// MFMA count 176 -> 96, weight ds_reads 48xb64 -> 24xb128, S chain-free.
__global__ __launch_bounds__(512, 4) void attn_mfma_kernel(
    const float* __restrict__ x,      // (NB, NA, DIN)
    const float* __restrict__ lap,    // (NB, NA)
    const float* __restrict__ W_in,   // (HID, DIN)
    const float* __restrict__ b_in,   // (HID)
    const float* __restrict__ Aq,     // (HID, HID)
    const float* __restrict__ Ak,     // (HID, HID)
    const float* __restrict__ Av,     // (HID, HID)
    const float* __restrict__ W_out,  // (DOUT, HID)
    const float* __restrict__ b_out,  // (DOUT)
    float* __restrict__ out)          // (NB, DOUT)
{
    // Paired frag-ordered f16 weights: [mat][it*2+c][lane][8]   (24 KB)
    // halves 0-3 = k-chunk 32c+4lg.., halves 4-7 = 32c+16+4lg..
    __shared__ _Float16 wlds[3][8][64][8];
    // Per-wave h transpose staging: [wave][jt][64][4]           (16 KB)
    __shared__ _Float16 hlds[8][4][64][4];

    const int t  = threadIdx.x;
    const int l  = t & 63;
    const int w  = t >> 6;          // 0..7
    const int lm = l & 15;
    const int lg = l >> 4;

    // ---- stage Aq/Ak/Av into LDS as paired f16 frags (wave w -> fid2=w) ----
    {
        const float* mats[3] = {Aq, Ak, Av};
        const int it = w >> 1, c = w & 1;
        #pragma unroll
        for (int m = 0; m < 3; ++m) {
            const float* base = mats[m] + (lm + 16 * it) * 64 + 32 * c + 4 * lg;
            v4f va = *(const v4f*)(base);
            v4f vb = *(const v4f*)(base + 16);
            *(v8h*)&wlds[m][w][l][0] = cvt8(va, vb);
        }
    }

    // ---- persistent register frags ----
    v4h zh = {};
    v4f zf = {};
    v4h winf[4];
    #pragma unroll
    for (int jt = 0; jt < 4; ++jt)
        winf[jt] = (lg < 2) ? cvt4(*(const v4f*)(W_in + (lm + 16 * jt) * 8 + 4 * lg)) : zh;
    v4h woutf[4];
    #pragma unroll
    for (int ks = 0; ks < 4; ++ks)
        woutf[ks] = (lm < 8) ? cvt4(*(const v4f*)(W_out + lm * 64 + 16 * ks + 4 * lg)) : zh;
    float binf[4];
    #pragma unroll
    for (int jt = 0; jt < 4; ++jt) binf[jt] = b_in[lm + 16 * jt];
    const float boutf = (lm < 8) ? b_out[lm] : 0.0f;

    __syncthreads();   // the only block barrier

    const int b = blockIdx.x * 8 + w;   // one item per wave, 1024*8 == NB

    v4f lapv[2];
    lapv[0] = *(const v4f*)(lap + b * 32 + 4 * lg);
    lapv[1] = *(const v4f*)(lap + b * 32 + 16 + 4 * lg);

    v4h xf[2];
    #pragma unroll
    for (int nt = 0; nt < 2; ++nt)
        xf[nt] = (lg < 2) ? cvt4(*(const v4f*)(x + b * 256 + (lm + 16 * nt) * 8 + 4 * lg)) : zh;

    // ---- h = silu(x @ W_in^T + b_in) * lap ; C->A transpose via swizzled LDS ----
    const int pr = l ^ lg;              // reader's swizzled row: l ^ ((l>>4)&3)
    v4h hf[2][4];
    #pragma unroll
    for (int nt = 0; nt < 2; ++nt) {
        #pragma unroll
        for (int jt = 0; jt < 4; ++jt) {
            v4f hc = MFMA16(xf[nt], winf[jt], zf);   // col j=lm+16jt, row n=4lg+r+16nt
            #pragma unroll
            for (int r = 0; r < 4; ++r) {
                float hv = silu_f(hc[r] + binf[jt]) * lapv[nt][r];
                const int lr   = (4 * lg + r) | ((lm >> 2) << 4);
                const int phys = lr ^ (lm >> 2);     // XOR swizzle (row ^ row>>4)
                hlds[w][jt][phys][lm & 3] = (_Float16)hv;
            }
        }
        __builtin_amdgcn_s_waitcnt(0);   // ds writes visible to same wave
        #pragma unroll
        for (int ks = 0; ks < 4; ++ks)
            hf[nt][ks] = *(v4h*)&hlds[w][ks][pr][0];
        __builtin_amdgcn_s_waitcnt(0);   // reads landed before next nt overwrites
    }
    // paired h frags: hf8[nt][c] covers j-chunk [32c, 32c+31]
    v8h hf8[2][2];
    #pragma unroll
    for (int nt = 0; nt < 2; ++nt)
        #pragma unroll
        for (int c = 0; c < 2; ++c)
            hf8[nt][c] = cat(hf[nt][2 * c], hf[nt][2 * c + 1]);

    // ---- QT[n][i] = silu(h @ Aq^T)  (K=32) ----
    v8h qf8[4];   // [it]: paired over the two n-halves
    {
        v4f acc[2][4] = {};
        #pragma unroll
        for (int it = 0; it < 4; ++it)
            #pragma unroll
            for (int c = 0; c < 2; ++c) {
                v8h bw = *(v8h*)&wlds[0][it * 2 + c][l][0];
                #pragma unroll
                for (int nt = 0; nt < 2; ++nt)
                    acc[nt][it] = MFMA32(hf8[nt][c], bw, acc[nt][it]);
            }
        #pragma unroll
        for (int it = 0; it < 4; ++it)
            qf8[it] = cat(silu_cvt4(acc[0][it]), silu_cvt4(acc[1][it]));
    }
    // ---- KT[n][i] = silu(h @ Ak^T) ----
    v8h kf8[4];   // [jt]
    {
        v4f acc[2][4] = {};
        #pragma unroll
        for (int it = 0; it < 4; ++it)
            #pragma unroll
            for (int c = 0; c < 2; ++c) {
                v8h bw = *(v8h*)&wlds[1][it * 2 + c][l][0];
                #pragma unroll
                for (int nt = 0; nt < 2; ++nt)
                    acc[nt][it] = MFMA32(hf8[nt][c], bw, acc[nt][it]);
            }
        #pragma unroll
        for (int it = 0; it < 4; ++it)
            kf8[it] = cat(silu_cvt4(acc[0][it]), silu_cvt4(acc[1][it]));
    }
    // ---- V[i][n] = silu(Av @ h^T) ----
    v8h vf8[2][2];   // [c][nt]: paired over j-chunks (V rows)
    {
        v4f acc[4][2] = {};
        #pragma unroll
        for (int it = 0; it < 4; ++it)
            #pragma unroll
            for (int c = 0; c < 2; ++c) {
                v8h aw = *(v8h*)&wlds[2][it * 2 + c][l][0];
                #pragma unroll
                for (int nt = 0; nt < 2; ++nt)
                    acc[it][nt] = MFMA32(aw, hf8[nt][c], acc[it][nt]);
            }
        #pragma unroll
        for (int c = 0; c < 2; ++c)
            #pragma unroll
            for (int nt = 0; nt < 2; ++nt)
                vf8[c][nt] = cat(silu_cvt4(acc[2 * c][nt]), silu_cvt4(acc[2 * c + 1][nt]));
    }

    // ---- streamed tail: per i-tile, S-col -> softmax -> PV -> Wout-acc ----
    v4f ya[2] = {};
    #pragma unroll
    for (int it = 0; it < 4; ++it) {
        // S^T column block: row j=4lg+r+16jt, col i=lm+16it (single K=32 MFMA each)
        v4f s[4];
        #pragma unroll
        for (int jt = 0; jt < 4; ++jt)
            s[jt] = MFMA32(kf8[jt], qf8[it], zf);

        // softmax over j (16 reg values + lane-groups 16/32)
        float mx = s[0][0];
        #pragma unroll
        for (int jt = 0; jt < 4; ++jt)
            #pragma unroll
            for (int r = 0; r < 4; ++r) mx = fmaxf(mx, s[jt][r]);
        mx = fmaxf(mx, __shfl_xor(mx, 16, 64));
        mx = fmaxf(mx, __shfl_xor(mx, 32, 64));
        float sum = 0.0f;
        #pragma unroll
        for (int jt = 0; jt < 4; ++jt)
            #pragma unroll
            for (int r = 0; r < 4; ++r) {
                float e = __expf(s[jt][r] - mx);
                s[jt][r] = e;
                sum += e;
            }
        sum += __shfl_xor(sum, 16, 64);
        sum += __shfl_xor(sum, 32, 64);
        const float inv = __fdividef(1.0f, sum);
        v4h pf[4];
        #pragma unroll
        for (int jt = 0; jt < 4; ++jt) pf[jt] = cvt4(s[jt] * inv);

        // PV for this i-tile: attnM[i][n] = P(i,j) @ V(j,n), K=32 over j-chunks
        v4f pv[2] = {};
        #pragma unroll
        for (int c = 0; c < 2; ++c) {
            v8h pf8 = cat(pf[2 * c], pf[2 * c + 1]);
            #pragma unroll
            for (int nt = 0; nt < 2; ++nt)
                pv[nt] = MFMA32(pf8, vf8[c][nt], pv[nt]);
        }

        // y-acc: ya[nt] += silu(attn) @ W_out^T (k-slice = this i-tile)
        #pragma unroll
        for (int nt = 0; nt < 2; ++nt)
            ya[nt] = MFMA16(silu_cvt4(pv[nt]), woutf[it], ya[nt]);
    }

    // ---- y = silu(ya + b_out) * lap ; mean over n ----
    float acc = 0.0f;
    #pragma unroll
    for (int nt = 0; nt < 2; ++nt)
        #pragma unroll
        for (int r = 0; r < 4; ++r)
            acc += silu_f(ya[nt][r] + boutf) * lapv[nt][r];
    acc += __shfl_xor(acc, 16, 64);
    acc += __shfl_xor(acc, 32, 64);
    if (l < 8) out[b * DOUT + l] = acc * (1.0f / NA);
}

extern "C" void kernel_launch(void* const* d_in, const int* in_sizes, int n_in,
                              void* d_out, int out_size, void* d_ws, size_t ws_size,
                              hipStream_t stream) {
    const float* x     = (const float*)d_in[0];
    const float* lap   = (const float*)d_in[1];
    const float* W_in  = (const float*)d_in[2];
    const float* b_in  = (const float*)d_in[3];
    const float* Aq    = (const float*)d_in[4];
    const float* Ak    = (const float*)d_in[5];
    const float* Av    = (const float*)d_in[6];
    const float* W_out = (const float*)d_in[7];
    const float* b_out = (const float*)d_in[8];
    attn_mfma_kernel<<<1024, 512, 0, stream>>>(x, lap, W_in, b_in, Aq, Ak, Av,
                                               W_out, b_out, (float*)d_out);
}

// Round 12
// 58.591 us; speedup vs baseline: 1.1158x; 1.0018x over previous
//
#include <hip/hip_runtime.h>

#define NB   8192
#define NA   32
#define DIN  8
#define HID  64
#define DOUT 8

typedef float     v4f __attribute__((ext_vector_type(4)));
typedef _Float16  v4h __attribute__((ext_vector_type(4)));
typedef _Float16  v8h __attribute__((ext_vector_type(8)));

__device__ __forceinline__ float silu_f(float x) {
    return __fdividef(x, 1.0f + __expf(-x));
}

__device__ __forceinline__ v4h cvt4(v4f a) {   // RNE converts
    v4h r;
    r[0] = (_Float16)a[0]; r[1] = (_Float16)a[1];
    r[2] = (_Float16)a[2]; r[3] = (_Float16)a[3];
    return r;
}

__device__ __forceinline__ v8h cvt8(v4f a, v4f b) {
    v8h r;
    r[0] = (_Float16)a[0]; r[1] = (_Float16)a[1];
    r[2] = (_Float16)a[2]; r[3] = (_Float16)a[3];
    r[4] = (_Float16)b[0]; r[5] = (_Float16)b[1];
    r[6] = (_Float16)b[2]; r[7] = (_Float16)b[3];
    return r;
}

__device__ __forceinline__ v4h silu_cvt4(v4f a) {
    v4f s;
    s[0] = silu_f(a[0]); s[1] = silu_f(a[1]);
    s[2] = silu_f(a[2]); s[3] = silu_f(a[3]);
    return cvt4(s);
}

__device__ __forceinline__ v8h cat(v4h a, v4h b) {
    return __builtin_shufflevector(a, b, 0, 1, 2, 3, 4, 5, 6, 7);
}

#define MFMA16(A, B, C) __builtin_amdgcn_mfma_f32_16x16x16f16((A), (B), (C), 0, 0, 0)
#define MFMA32(A, B, C) __builtin_amdgcn_mfma_f32_16x16x32_f16((A), (B), (C), 0, 0, 0)

// One wave = one batch item, fully in MFMA fragments; ZERO per-item LDS.
// The h-gemm is computed SWAPPED (W_in @ x^T): its C-frag (lane=n, reg=j)
// is directly the A/B operand layout for the Q/K/V gemms -> the LDS
// transpose (32 ds_write + 8 ds_read + 2 waitcnt drains) is deleted.
// Bias folds into the MFMA: winf k=8 element = b_in[j], xf k=8 element = 1.
__global__ __launch_bounds__(512, 4) void attn_mfma_kernel(
    const float* __restrict__ x,      // (NB, NA, DIN)
    const float* __restrict__ lap,    // (NB, NA)
    const float* __restrict__ W_in,   // (HID, DIN)
    const float* __restrict__ b_in,   // (HID)
    const float* __restrict__ Aq,     // (HID, HID)
    const float* __restrict__ Ak,     // (HID, HID)
    const float* __restrict__ Av,     // (HID, HID)
    const float* __restrict__ W_out,  // (DOUT, HID)
    const float* __restrict__ b_out,  // (DOUT)
    float* __restrict__ out)          // (NB, DOUT)
{
    // Paired frag-ordered f16 weights: [mat][it*2+c][lane][8]   (24 KB)
    __shared__ _Float16 wlds[3][8][64][8];

    const int t  = threadIdx.x;
    const int l  = t & 63;
    const int w  = t >> 6;          // 0..7
    const int lm = l & 15;
    const int lg = l >> 4;

    // ---- stage Aq/Ak/Av into LDS as paired f16 frags (wave w -> fid2=w) ----
    {
        const float* mats[3] = {Aq, Ak, Av};
        const int it = w >> 1, c = w & 1;
        #pragma unroll
        for (int m = 0; m < 3; ++m) {
            const float* base = mats[m] + (lm + 16 * it) * 64 + 32 * c + 4 * lg;
            v4f va = *(const v4f*)(base);
            v4f vb = *(const v4f*)(base + 16);
            *(v8h*)&wlds[m][w][l][0] = cvt8(va, vb);
        }
    }

    // ---- persistent register frags ----
    v4h zh = {};
    v4f zf = {};
    // winf[jt]: A-frag of W_in row j=lm+16jt, k=d=4lg+r; k=8 slot = b_in[j]
    v4h winf[4];
    #pragma unroll
    for (int jt = 0; jt < 4; ++jt) {
        v4h wf = zh;
        if (lg < 2)       wf = cvt4(*(const v4f*)(W_in + (lm + 16 * jt) * 8 + 4 * lg));
        else if (lg == 2) wf[0] = (_Float16)b_in[lm + 16 * jt];
        winf[jt] = wf;
    }
    v4h woutf[4];
    #pragma unroll
    for (int ks = 0; ks < 4; ++ks)
        woutf[ks] = (lm < 8) ? cvt4(*(const v4f*)(W_out + lm * 64 + 16 * ks + 4 * lg)) : zh;
    const float boutf = (lm < 8) ? b_out[lm] : 0.0f;
    v4h onef = zh;
    if (lg == 2) onef[0] = (_Float16)1.0f;   // the k=8 "bias column" of x

    __syncthreads();   // the only block barrier

    const int b = blockIdx.x * 8 + w;   // one item per wave, 1024*8 == NB

    v4f lapv[2];                         // lap by row n=4lg+r+16nt (epilogue)
    lapv[0] = *(const v4f*)(lap + b * 32 + 4 * lg);
    lapv[1] = *(const v4f*)(lap + b * 32 + 16 + 4 * lg);
    float lap_n[2];                      // lap by lane n=lm+16nt (h stage)
    lap_n[0] = lap[b * 32 + lm];
    lap_n[1] = lap[b * 32 + 16 + lm];

    // xf[nt]: B-frag x^T[k=d][n=lm+16nt]; k=8 slot = 1.0 (bias column)
    v4h xf[2];
    #pragma unroll
    for (int nt = 0; nt < 2; ++nt)
        xf[nt] = (lg < 2) ? cvt4(*(const v4f*)(x + b * 256 + (lm + 16 * nt) * 8 + 4 * lg))
                          : onef;

    // ---- h^T directly: C[jt][nt] reg r = h[n=lm+16nt][j=4lg+r+16jt] ----
    v4h hf[2][4];
    #pragma unroll
    for (int nt = 0; nt < 2; ++nt)
        #pragma unroll
        for (int jt = 0; jt < 4; ++jt) {
            v4f hc = MFMA16(winf[jt], xf[nt], zf);
            v4f s;
            #pragma unroll
            for (int r = 0; r < 4; ++r) s[r] = silu_f(hc[r]) * lap_n[nt];
            hf[nt][jt] = cvt4(s);
        }
    // paired h frags: hf8[nt][c] covers j-chunk [32c, 32c+31]
    v8h hf8[2][2];
    #pragma unroll
    for (int nt = 0; nt < 2; ++nt)
        #pragma unroll
        for (int c = 0; c < 2; ++c)
            hf8[nt][c] = cat(hf[nt][2 * c], hf[nt][2 * c + 1]);

    // ---- QT[n][i] = silu(h @ Aq^T)  (K=32) ----
    v8h qf8[4];   // [it]: paired over the two n-halves
    {
        v4f acc[2][4] = {};
        #pragma unroll
        for (int it = 0; it < 4; ++it)
            #pragma unroll
            for (int c = 0; c < 2; ++c) {
                v8h bw = *(v8h*)&wlds[0][it * 2 + c][l][0];
                #pragma unroll
                for (int nt = 0; nt < 2; ++nt)
                    acc[nt][it] = MFMA32(hf8[nt][c], bw, acc[nt][it]);
            }
        #pragma unroll
        for (int it = 0; it < 4; ++it)
            qf8[it] = cat(silu_cvt4(acc[0][it]), silu_cvt4(acc[1][it]));
    }
    // ---- KT[n][i] = silu(h @ Ak^T) ----
    v8h kf8[4];   // [jt]
    {
        v4f acc[2][4] = {};
        #pragma unroll
        for (int it = 0; it < 4; ++it)
            #pragma unroll
            for (int c = 0; c < 2; ++c) {
                v8h bw = *(v8h*)&wlds[1][it * 2 + c][l][0];
                #pragma unroll
                for (int nt = 0; nt < 2; ++nt)
                    acc[nt][it] = MFMA32(hf8[nt][c], bw, acc[nt][it]);
            }
        #pragma unroll
        for (int it = 0; it < 4; ++it)
            kf8[it] = cat(silu_cvt4(acc[0][it]), silu_cvt4(acc[1][it]));
    }
    // ---- V[i][n] = silu(Av @ h^T) ----
    v8h vf8[2][2];   // [c][nt]: paired over j-chunks (V rows)
    {
        v4f acc[4][2] = {};
        #pragma unroll
        for (int it = 0; it < 4; ++it)
            #pragma unroll
            for (int c = 0; c < 2; ++c) {
                v8h aw = *(v8h*)&wlds[2][it * 2 + c][l][0];
                #pragma unroll
                for (int nt = 0; nt < 2; ++nt)
                    acc[it][nt] = MFMA32(aw, hf8[nt][c], acc[it][nt]);
            }
        #pragma unroll
        for (int c = 0; c < 2; ++c)
            #pragma unroll
            for (int nt = 0; nt < 2; ++nt)
                vf8[c][nt] = cat(silu_cvt4(acc[2 * c][nt]), silu_cvt4(acc[2 * c + 1][nt]));
    }

    // ---- streamed tail: per i-tile, S-col -> softmax -> PV -> Wout-acc ----
    v4f ya[2] = {};
    #pragma unroll
    for (int it = 0; it < 4; ++it) {
        // S^T column block: row j=4lg+r+16jt, col i=lm+16it (single K=32 MFMA each)
        v4f s[4];
        #pragma unroll
        for (int jt = 0; jt < 4; ++jt)
            s[jt] = MFMA32(kf8[jt], qf8[it], zf);

        // softmax over j (16 reg values + lane-groups 16/32)
        float mx = s[0][0];
        #pragma unroll
        for (int jt = 0; jt < 4; ++jt)
            #pragma unroll
            for (int r = 0; r < 4; ++r) mx = fmaxf(mx, s[jt][r]);
        mx = fmaxf(mx, __shfl_xor(mx, 16, 64));
        mx = fmaxf(mx, __shfl_xor(mx, 32, 64));
        float sum = 0.0f;
        #pragma unroll
        for (int jt = 0; jt < 4; ++jt)
            #pragma unroll
            for (int r = 0; r < 4; ++r) {
                float e = __expf(s[jt][r] - mx);
                s[jt][r] = e;
                sum += e;
            }
        sum += __shfl_xor(sum, 16, 64);
        sum += __shfl_xor(sum, 32, 64);
        const float inv = __fdividef(1.0f, sum);
        v4h pf[4];
        #pragma unroll
        for (int jt = 0; jt < 4; ++jt) pf[jt] = cvt4(s[jt] * inv);

        // PV for this i-tile: attnM[i][n] = P(i,j) @ V(j,n), K=32 over j-chunks
        v4f pv[2] = {};
        #pragma unroll
        for (int c = 0; c < 2; ++c) {
            v8h pf8 = cat(pf[2 * c], pf[2 * c + 1]);
            #pragma unroll
            for (int nt = 0; nt < 2; ++nt)
                pv[nt] = MFMA32(pf8, vf8[c][nt], pv[nt]);
        }

        // y-acc: ya[nt] += silu(attn) @ W_out^T (k-slice = this i-tile)
        #pragma unroll
        for (int nt = 0; nt < 2; ++nt)
            ya[nt] = MFMA16(silu_cvt4(pv[nt]), woutf[it], ya[nt]);
    }

    // ---- y = silu(ya + b_out) * lap ; mean over n ----
    float acc = 0.0f;
    #pragma unroll
    for (int nt = 0; nt < 2; ++nt)
        #pragma unroll
        for (int r = 0; r < 4; ++r)
            acc += silu_f(ya[nt][r] + boutf) * lapv[nt][r];
    acc += __shfl_xor(acc, 16, 64);
    acc += __shfl_xor(acc, 32, 64);
    if (l < 8) out[b * DOUT + l] = acc * (1.0f / NA);
}

extern "C" void kernel_launch(void* const* d_in, const int* in_sizes, int n_in,
                              void* d_out, int out_size, void* d_ws, size_t ws_size,
                              hipStream_t stream) {
    const float* x     = (const float*)d_in[0];
    const float* lap   = (const float*)d_in[1];
    const float* W_in  = (const float*)d_in[2];
    const float* b_in  = (const float*)d_in[3];
    const float* Aq    = (const float*)d_in[4];
    const float* Ak    = (const float*)d_in[5];
    const float* Av    = (const float*)d_in[6];
    const float* W_out = (const float*)d_in[7];
    const float* b_out = (const float*)d_in[8];
    attn_mfma_kernel<<<1024, 512, 0, stream>>>(x, lap, W_in, b_in, Aq, Ak, Av,
                                               W_out, b_out, (float*)d_out);
}